// Round 12
// baseline (2239.278 us; speedup 1.0000x reference)
//
#include <hip/hip_runtime.h>
#include <hip/hip_bf16.h>

#define NT 512
typedef unsigned short u16;
typedef short s16x8 __attribute__((ext_vector_type(8)));
typedef float f32x4 __attribute__((ext_vector_type(4)));

constexpr int B_ = 2048, N_ = 64, S_ = 65, D_ = 256, L_ = 3;

// ---- workspace layout ----
constexpr size_t CW1T_OFF = 0;              // [256][768]
constexpr size_t CW2T_OFF = 196608;         // [256][256]
constexpr size_t QKVWT_OFF = 262144;        // [3][768][256]
constexpr size_t AOWT_OFF = 851968;         // [3][256][256]
constexpr size_t FW1T_OFF = 1048576;        // [3][1024][256]
constexpr size_t FW2T_OFF = 1835008;        // [3][256][1024]
constexpr size_t WS_W_BYTES = 5242880;
constexpr size_t X_OFF     = WS_W_BYTES;               // x bf16 [133120][256]
constexpr size_t OSLOT_OFF = X_OFF + 68157440;         // G1 / o / delta2
constexpr size_t BIG_OFF   = OSLOT_OFF + 68157440;     // T / qkv / delta
constexpr size_t WS_NEEDED = BIG_OFF + 272629760;      // ≈ 395 MB

#define MFMA16(a, b, c) __builtin_amdgcn_mfma_f32_16x16x32_bf16(a, b, c, 0, 0, 0)

typedef __attribute__((address_space(3))) unsigned int lds_uint;
typedef __attribute__((address_space(1))) const unsigned int glb_uint;
// async global->LDS copy: lane l writes lds + l*16B; lds base must be
// wave-uniform; global address is per-lane.
__device__ __forceinline__ void gload_lds16(const void* g, void* l) {
  __builtin_amdgcn_global_load_lds((glb_uint*)g, (lds_uint*)l, 16, 0, 0);
}

__device__ __forceinline__ u16 f2b(float f) {
  __hip_bfloat16 h = __float2bfloat16(f);
  return *reinterpret_cast<u16*>(&h);
}
__device__ __forceinline__ float b2f(u16 u) { return __uint_as_float(((unsigned)u) << 16); }
__device__ __forceinline__ float sigm(float x) { return 1.0f / (1.0f + __expf(-x)); }

__device__ __forceinline__ float wave_sum(float v) {
#pragma unroll
  for (int o = 32; o > 0; o >>= 1) v += __shfl_xor(v, o);
  return v;
}
__device__ __forceinline__ float wave_max(float v) {
#pragma unroll
  for (int o = 32; o > 0; o >>= 1) v = fmaxf(v, __shfl_xor(v, o));
  return v;
}
__device__ __forceinline__ void unpack8(const u16* p, float* f) {
  uint4 u = *reinterpret_cast<const uint4*>(p);
  f[0] = __uint_as_float(u.x << 16); f[1] = __uint_as_float(u.x & 0xffff0000u);
  f[2] = __uint_as_float(u.y << 16); f[3] = __uint_as_float(u.y & 0xffff0000u);
  f[4] = __uint_as_float(u.z << 16); f[5] = __uint_as_float(u.z & 0xffff0000u);
  f[6] = __uint_as_float(u.w << 16); f[7] = __uint_as_float(u.w & 0xffff0000u);
}

// transpose-convert: src [K][N] f32 -> dst [N][K] bf16 (batched over blockIdx.y)
__global__ void wconv(const float* __restrict__ src, u16* __restrict__ dst, int K, int N) {
  const size_t bo = (size_t)blockIdx.y * K * N;
  int idx = blockIdx.x * 256 + threadIdx.x;
  if (idx >= K * N) return;
  int n = idx / K, k = idx - n * K;
  dst[bo + idx] = f2b(src[bo + (size_t)k * N + n]);
}

// =====================================================================
// Phase-split path
// =====================================================================

// C[m][n] = sum_k A[m][k]*Bt[n][k].  128x256 tile, 8 waves (2x4 wave grid,
// each wave 64x64 / acc[4][4]).  global_load_lds staging, XCD swizzle.
// EPI: 0 plain; 1 +bias; 2 silu(+bias); 3 +bias, strided x-row write.
template <int M, int N, int K, int EPI>
__global__ __launch_bounds__(512, 4) void gemm_bt(
    const u16* __restrict__ A, const u16* __restrict__ Bt,
    const float* __restrict__ bias, u16* __restrict__ C) {
  constexpr int MT_ = M / 128, NT_ = N / 256;
  constexpr int CHUNK = (MT_ * NT_) / 8;   // all grids divisible by 8
  const int logical = (blockIdx.x % 8) * CHUNK + blockIdx.x / 8;
  const int mt = logical / NT_, nt = logical % NT_;
  const int m0 = mt * 128, n0 = nt * 256;
  const int tid = threadIdx.x, lane = tid & 63, w = tid >> 6;
  const int lr = lane & 15, lg = lane >> 4;
  const int wr = w >> 2, wc = w & 3;   // wave grid: 2 row-tiles x 4 col-tiles

  __shared__ __align__(16) u16 sm[64 * 264];  // K: As[4096]|Bs[8192]; epi: Cs[64][264]
  u16* As = sm;          // [128][32]
  u16* Bs = sm + 4096;   // [256][32]
  f32x4 acc[4][4] = {};

  const int arow = w * 16 + (lane >> 2);
  const int brow = w * 32 + (lane >> 2);
  const int scol = (lane & 3) * 8;

  for (int k0 = 0; k0 < K; k0 += 32) {
    __syncthreads();
    gload_lds16(&A[(size_t)(m0 + arow) * K + k0 + scol],       &As[(w * 16) * 32]);
    gload_lds16(&Bt[(size_t)(n0 + brow) * K + k0 + scol],      &Bs[(w * 32) * 32]);
    gload_lds16(&Bt[(size_t)(n0 + brow + 16) * K + k0 + scol], &Bs[(w * 32 + 16) * 32]);
    __syncthreads();
    s16x8 af[4], bf[4];
#pragma unroll
    for (int i = 0; i < 4; ++i)
      af[i] = *(const s16x8*)&As[(wr * 64 + i * 16 + lr) * 32 + lg * 8];
#pragma unroll
    for (int j = 0; j < 4; ++j)
      bf[j] = *(const s16x8*)&Bs[(wc * 64 + j * 16 + lr) * 32 + lg * 8];
#pragma unroll
    for (int i = 0; i < 4; ++i)
#pragma unroll
      for (int j = 0; j < 4; ++j)
        acc[i][j] = MFMA16(af[i], bf[j], acc[i][j]);
  }

#pragma unroll
  for (int h = 0; h < 2; ++h) {
    __syncthreads();
    if (wr == h) {
#pragma unroll
      for (int j = 0; j < 4; ++j) {
        const int nl = wc * 64 + j * 16 + lr;
        const float bb = (EPI == 0) ? 0.0f : bias[n0 + nl];
#pragma unroll
        for (int i = 0; i < 4; ++i)
#pragma unroll
          for (int e = 0; e < 4; ++e) {
            float v = acc[i][j][e] + bb;
            if (EPI == 2) v = v * sigm(v);
            sm[(i * 16 + lg * 4 + e) * 264 + nl] = f2b(v);
          }
      }
    }
    __syncthreads();
    const int mbase = m0 + h * 64;
    const size_t gbase = (EPI == 3) ? (size_t)((mbase >> 6) * 65 + 1) : (size_t)mbase;
    for (int idx = tid; idx < 64 * 32; idx += 512) {
      int row = idx >> 5, c8 = idx & 31;
      *(uint4*)&C[(gbase + row) * N + n0 + c8 * 8] = *(const uint4*)&sm[row * 264 + c8 * 8];
    }
  }
}

// Fused FFN: outd[m][0:256] = silu(x @ W1 + b1) @ W2   (no b2 — resln adds it)
// Block = 64 rows, 256 threads / 4 waves, 8 chunks of 128 h1-cols.
// h1 never touches HBM (was 273 MB write + read per layer).
// LDS 67.6 KB -> 2 blocks/CU at (256,2); acc_out 64 + acc1 32 VGPR, 256 budget.
__global__ __launch_bounds__(256, 2) void ffn_fused(
    const u16* __restrict__ x, const u16* __restrict__ W1t,   // [1024][256]
    const float* __restrict__ b1, const u16* __restrict__ W2t,// [256][1024]
    u16* __restrict__ outd) {
  constexpr int CHUNK_SW = 2080 / 8;
  const int logical = (blockIdx.x % 8) * CHUNK_SW + blockIdx.x / 8;
  const int m0 = logical * 64;
  const int tid = threadIdx.x, lane = tid & 63, w = tid >> 6;
  const int lr = lane & 15, lg = lane >> 4;
  const int wr = w >> 1, wc = w & 1;       // phase-1 wave grid 2x2
  const int g_sub = lane >> 2, g_col = (lane & 3) * 8;  // gload lane map

  __shared__ __align__(16) u16 xs[64 * 264];   // x tile (padded); epi: Cs
  __shared__ __align__(16) u16 h1s[64 * 136];  // h1 chunk (padded)
  __shared__ __align__(16) u16 Bs[256 * 32];   // weight k-tile (both phases)

  // stage x tile once (reg-staged into padded layout)
  for (int idx = tid; idx < 64 * 32; idx += 256) {
    int row = idx >> 5, c8 = idx & 31;
    *(uint4*)&xs[row * 264 + c8 * 8] =
        *(const uint4*)&x[(size_t)(m0 + row) * 256 + c8 * 8];
  }

  f32x4 aout[4][4] = {};

  for (int c = 0; c < 8; ++c) {
    // ---- phase 1: h1c[64][128] = silu(x @ W1 rows [c*128,+128) + b1) ----
    f32x4 a1[2][4] = {};
    for (int k0 = 0; k0 < 256; k0 += 32) {
      __syncthreads();  // Bs free; (first iter also covers x-stage + h1 readers)
      gload_lds16(&W1t[(size_t)(c * 128 + w * 32 + g_sub) * 256 + k0 + g_col],
                  &Bs[(w * 32) * 32]);
      gload_lds16(&W1t[(size_t)(c * 128 + w * 32 + 16 + g_sub) * 256 + k0 + g_col],
                  &Bs[(w * 32 + 16) * 32]);
      __syncthreads();
      s16x8 af[2], bf[4];
#pragma unroll
      for (int i = 0; i < 2; ++i)
        af[i] = *(const s16x8*)&xs[(wr * 32 + i * 16 + lr) * 264 + k0 + lg * 8];
#pragma unroll
      for (int j = 0; j < 4; ++j)
        bf[j] = *(const s16x8*)&Bs[(wc * 64 + j * 16 + lr) * 32 + lg * 8];
#pragma unroll
      for (int i = 0; i < 2; ++i)
#pragma unroll
        for (int j = 0; j < 4; ++j)
          a1[i][j] = MFMA16(af[i], bf[j], a1[i][j]);
    }
    // write h1c (bias + silu).  Prev phase-2 h1 readers are long done
    // (multiple barriers since).  Visibility to phase 2 via its first bar.
#pragma unroll
    for (int j = 0; j < 4; ++j) {
      const int ncol = wc * 64 + j * 16 + lr;
      const float bb = b1[c * 128 + ncol];
#pragma unroll
      for (int i = 0; i < 2; ++i)
#pragma unroll
        for (int e = 0; e < 4; ++e) {
          const int row = wr * 32 + i * 16 + lg * 4 + e;
          float v = a1[i][j][e] + bb;
          h1s[row * 136 + ncol] = f2b(v * sigm(v));
        }
    }
    // ---- phase 2: aout += h1c @ W2 cols [c*128,+128) ----
    for (int kk = 0; kk < 128; kk += 32) {
      __syncthreads();  // h1 writes visible; Bs free
      gload_lds16(&W2t[(size_t)(w * 64 + g_sub) * 1024 + c * 128 + kk + g_col],
                  &Bs[(w * 64) * 32]);
      gload_lds16(&W2t[(size_t)(w * 64 + 16 + g_sub) * 1024 + c * 128 + kk + g_col],
                  &Bs[(w * 64 + 16) * 32]);
      gload_lds16(&W2t[(size_t)(w * 64 + 32 + g_sub) * 1024 + c * 128 + kk + g_col],
                  &Bs[(w * 64 + 32) * 32]);
      gload_lds16(&W2t[(size_t)(w * 64 + 48 + g_sub) * 1024 + c * 128 + kk + g_col],
                  &Bs[(w * 64 + 48) * 32]);
      __syncthreads();
      s16x8 af[4], bf[4];
#pragma unroll
      for (int i = 0; i < 4; ++i)
        af[i] = *(const s16x8*)&h1s[(i * 16 + lr) * 136 + kk + lg * 8];
#pragma unroll
      for (int j = 0; j < 4; ++j)
        bf[j] = *(const s16x8*)&Bs[(w * 64 + j * 16 + lr) * 32 + lg * 8];
#pragma unroll
      for (int i = 0; i < 4; ++i)
#pragma unroll
        for (int j = 0; j < 4; ++j)
          aout[i][j] = MFMA16(af[i], bf[j], aout[i][j]);
    }
  }

  // epilogue: stage through xs (x dead), coalesced stores
  __syncthreads();
#pragma unroll
  for (int j = 0; j < 4; ++j) {
    const int ncol = w * 64 + j * 16 + lr;
#pragma unroll
    for (int i = 0; i < 4; ++i)
#pragma unroll
      for (int e = 0; e < 4; ++e)
        xs[(i * 16 + lg * 4 + e) * 264 + ncol] = f2b(aout[i][j][e]);
  }
  __syncthreads();
  for (int idx = tid; idx < 64 * 32; idx += 256) {
    int row = idx >> 5, c8 = idx & 31;
    *(uint4*)&outd[(size_t)(m0 + row) * 256 + c8 * 8] =
        *(const uint4*)&xs[row * 264 + c8 * 8];
  }
}

// x = LN(x + delta + cbias) row-wise; 133120 rows  [round-4 proven version]
__global__ __launch_bounds__(256) void resln(
    u16* __restrict__ x, const u16* __restrict__ delta,
    const float* __restrict__ cbias, const float* __restrict__ g,
    const float* __restrict__ bb) {
  const int lane = threadIdx.x & 63, w = threadIdx.x >> 6;
  const float4 gv = *(const float4*)&g[lane * 4];
  const float4 bv = *(const float4*)&bb[lane * 4];
  const float4 cb = *(const float4*)&cbias[lane * 4];
  for (int r = blockIdx.x * 4 + w; r < 133120; r += 8192) {
    uint2 xu = *(const uint2*)&x[(size_t)r * 256 + lane * 4];
    uint2 du = *(const uint2*)&delta[(size_t)r * 256 + lane * 4];
    float v0 = __uint_as_float(xu.x << 16) + __uint_as_float(du.x << 16) + cb.x;
    float v1 = __uint_as_float(xu.x & 0xffff0000u) + __uint_as_float(du.x & 0xffff0000u) + cb.y;
    float v2 = __uint_as_float(xu.y << 16) + __uint_as_float(du.y << 16) + cb.z;
    float v3 = __uint_as_float(xu.y & 0xffff0000u) + __uint_as_float(du.y & 0xffff0000u) + cb.w;
    float mean = wave_sum(v0 + v1 + v2 + v3) * (1.0f / 256.0f);
    float d0 = v0 - mean, d1 = v1 - mean, d2 = v2 - mean, d3 = v3 - mean;
    float var = wave_sum(d0 * d0 + d1 * d1 + d2 * d2 + d3 * d3) * (1.0f / 256.0f);
    float rs = rsqrtf(var + 1e-5f);
    uint2 p;
    p.x = f2b(d0 * rs * gv.x + bv.x) | ((unsigned)f2b(d1 * rs * gv.y + bv.y) << 16);
    p.y = f2b(d2 * rs * gv.z + bv.z) | ((unsigned)f2b(d3 * rs * gv.w + bv.w) << 16);
    *(uint2*)&x[(size_t)r * 256 + lane * 4] = p;
  }
}

// Build T [131072][768] bf16: concat(edge-proj, nbr_table gather, msgs)
__global__ __launch_bounds__(512) void embed_k(
    const float* __restrict__ msgs, const float* __restrict__ edge_vec,
    const float* __restrict__ edge_dist, const int* __restrict__ enb,
    const float* __restrict__ edge_w, const float* __restrict__ edge_b,
    const float* __restrict__ nbr_table, u16* __restrict__ T) {
  const int r0 = blockIdx.x * 64, tid = threadIdx.x;
  __shared__ float tv[64][4];
  if (tid < 256) {
    int r = tid >> 2, j = tid & 3;
    tv[r][j] = (j < 3) ? edge_vec[(size_t)(r0 + r) * 3 + j] : edge_dist[r0 + r];
  }
  __syncthreads();
  for (int idx = tid; idx < 64 * 192; idx += 512) {
    int r = idx / 192, c4 = (idx % 192) * 4;
    size_t gn = (size_t)r0 + r;
    float4 v;
    if (c4 < 256) {
      float t0 = tv[r][0], t1 = tv[r][1], t2 = tv[r][2], t3 = tv[r][3];
      const float4 w0 = *(const float4*)&edge_w[c4];
      const float4 w1 = *(const float4*)&edge_w[256 + c4];
      const float4 w2 = *(const float4*)&edge_w[512 + c4];
      const float4 w3 = *(const float4*)&edge_w[768 + c4];
      const float4 eb4 = *(const float4*)&edge_b[c4];
      v.x = t0 * w0.x + t1 * w1.x + t2 * w2.x + t3 * w3.x + eb4.x;
      v.y = t0 * w0.y + t1 * w1.y + t2 * w2.y + t3 * w3.y + eb4.y;
      v.z = t0 * w0.z + t1 * w1.z + t2 * w2.z + t3 * w3.z + eb4.z;
      v.w = t0 * w0.w + t1 * w1.w + t2 * w2.w + t3 * w3.w + eb4.w;
    } else if (c4 < 512) {
      v = *(const float4*)&nbr_table[(size_t)enb[gn] * 256 + (c4 - 256)];
    } else {
      v = *(const float4*)&msgs[gn * 256 + (c4 - 512)];
    }
    uint2 p;
    p.x = f2b(v.x) | ((unsigned)f2b(v.y) << 16);
    p.y = f2b(v.z) | ((unsigned)f2b(v.w) << 16);
    *(uint2*)&T[gn * 768 + c4] = p;
  }
}

// node row s=0 per batch
__global__ __launch_bounds__(256) void node_row(
    const float* __restrict__ momenta, const int* __restrict__ ein,
    const float* __restrict__ node_table, const float* __restrict__ mom_w,
    const float* __restrict__ mom_b, const float* __restrict__ ncw,
    const float* __restrict__ ncb, u16* __restrict__ x) {
  const int b = blockIdx.x, tid = threadIdx.x;
  __shared__ float cvec[512];
  cvec[tid] = node_table[(size_t)ein[b] * 256 + tid];
  float m0 = momenta[b * 3], m1 = momenta[b * 3 + 1], m2 = momenta[b * 3 + 2];
  cvec[256 + tid] = m0 * mom_w[tid] + m1 * mom_w[256 + tid] + m2 * mom_w[512 + tid] + mom_b[tid];
  __syncthreads();
  float acc = 0.0f;
  for (int k = 0; k < 512; k += 4) {
    const float4 cv = *(const float4*)&cvec[k];
    acc += cv.x * ncw[(k + 0) * 256 + tid] + cv.y * ncw[(k + 1) * 256 + tid] +
           cv.z * ncw[(k + 2) * 256 + tid] + cv.w * ncw[(k + 3) * 256 + tid];
  }
  x[(size_t)b * 65 * 256 + tid] = f2b(acc + ncb[tid]);
}

// MFMA attention: block = (b, head-pair), 4 waves, 2 waves per head.
__global__ __launch_bounds__(256, 2) void attn_k2(
    const u16* __restrict__ qkv, const float* __restrict__ cutoff,
    u16* __restrict__ o) {
  const int b = blockIdx.x, hp = blockIdx.y;
  const int tid = threadIdx.x, lane = tid & 63, w = tid >> 6;
  const int lr = lane & 15, lg = lane >> 4;
  const int hl = w >> 1, wp = w & 1;
  const size_t bs0 = (size_t)b * 65;

  __shared__ __align__(16) u16 Qs[2][80][40];
  __shared__ __align__(16) u16 Ks[2][80][40];
  __shared__ __align__(16) u16 Vt[2][32][104];
  __shared__ __align__(16) u16 Ps[2][80][104];
  __shared__ float bias_s[80];

  if (tid < 80) {
    float bv;
    if (tid == 0) bv = 0.0f;
    else if (tid < 65) {
      float cf = cutoff[b * 64 + tid - 1];
      bv = (cf > 0.0f) ? logf(fmaxf(cf, 1e-30f)) : -1e9f;
    } else bv = -1e9f;
    bias_s[tid] = bv;
  }
  for (int idx = tid; idx < 2 * 80 * 4; idx += 256) {
    int h2 = idx / 320, rem = idx - h2 * 320;
    int q = rem >> 2, j = rem & 3;
    *(uint2*)&Ps[h2][q][80 + j * 4] = make_uint2(0, 0);
  }
  for (int idx = tid; idx < 2 * 32 * 4; idx += 256) {
    int h2 = idx / 128, rem = idx - h2 * 128;
    int d = rem >> 2, j = rem & 3;
    *(uint2*)&Vt[h2][d][80 + j * 4] = make_uint2(0, 0);
  }
  for (int idx = tid; idx < 2 * 80 * 8; idx += 256) {
    int h2 = idx / 640, rem = idx - h2 * 640;
    int s = rem >> 3, c4 = (rem & 7) << 2;
    uint2 vq = make_uint2(0, 0), vk = vq, vv = vq;
    if (s < 65) {
      const u16* base = qkv + (bs0 + s) * 768 + (hp * 2 + h2) * 32 + c4;
      vq = *(const uint2*)(base);
      vk = *(const uint2*)(base + 256);
      vv = *(const uint2*)(base + 512);
    }
    *(uint2*)&Qs[h2][s][c4] = vq;
    *(uint2*)&Ks[h2][s][c4] = vk;
    Vt[h2][c4 + 0][s] = (u16)(vv.x & 0xffffu);
    Vt[h2][c4 + 1][s] = (u16)(vv.x >> 16);
    Vt[h2][c4 + 2][s] = (u16)(vv.y & 0xffffu);
    Vt[h2][c4 + 3][s] = (u16)(vv.y >> 16);
  }
  __syncthreads();

  const int nt0 = wp ? 3 : 0, nt1 = wp ? 5 : 3;
  for (int nt = nt0; nt < nt1; ++nt) {
    s16x8 bq = *(const s16x8*)&Qs[hl][nt * 16 + lr][lg * 8];
    f32x4 sacc[5];
#pragma unroll
    for (int mt = 0; mt < 5; ++mt) {
      s16x8 ak = *(const s16x8*)&Ks[hl][mt * 16 + lr][lg * 8];
      f32x4 z = {0.f, 0.f, 0.f, 0.f};
      sacc[mt] = MFMA16(ak, bq, z);
    }
    float pv[5][4];
    float cmax = -3e38f;
#pragma unroll
    for (int mt = 0; mt < 5; ++mt)
#pragma unroll
      for (int e = 0; e < 4; ++e) {
        float v = sacc[mt][e] * 0.17677669529663687f + bias_s[mt * 16 + lg * 4 + e];
        pv[mt][e] = v;
        cmax = fmaxf(cmax, v);
      }
    cmax = fmaxf(cmax, __shfl_xor(cmax, 16));
    cmax = fmaxf(cmax, __shfl_xor(cmax, 32));
    float csum = 0.f;
#pragma unroll
    for (int mt = 0; mt < 5; ++mt)
#pragma unroll
      for (int e = 0; e < 4; ++e) {
        float p = __expf(pv[mt][e] - cmax);
        pv[mt][e] = p;
        csum += p;
      }
    csum += __shfl_xor(csum, 16);
    csum += __shfl_xor(csum, 32);
    float rinv = 1.0f / csum;
    const int q = nt * 16 + lr;
#pragma unroll
    for (int mt = 0; mt < 5; ++mt) {
      uint2 pk;
      pk.x = (unsigned)f2b(pv[mt][0] * rinv) | ((unsigned)f2b(pv[mt][1] * rinv) << 16);
      pk.y = (unsigned)f2b(pv[mt][2] * rinv) | ((unsigned)f2b(pv[mt][3] * rinv) << 16);
      *(uint2*)&Ps[hl][q][mt * 16 + lg * 4] = pk;
    }
  }
  __syncthreads();

  s16x8 vb[2][3];
#pragma unroll
  for (int d2 = 0; d2 < 2; ++d2)
#pragma unroll
    for (int ks = 0; ks < 3; ++ks)
      vb[d2][ks] = *(const s16x8*)&Vt[hl][d2 * 16 + lr][ks * 32 + lg * 8];
  const int mt0 = wp ? 3 : 0, mt1 = wp ? 5 : 3;
  for (int mt = mt0; mt < mt1; ++mt) {
    f32x4 oa[2] = {};
#pragma unroll
    for (int ks = 0; ks < 3; ++ks) {
      s16x8 pa = *(const s16x8*)&Ps[hl][mt * 16 + lr][ks * 32 + lg * 8];
#pragma unroll
      for (int d2 = 0; d2 < 2; ++d2) oa[d2] = MFMA16(pa, vb[d2][ks], oa[d2]);
    }
#pragma unroll
    for (int e = 0; e < 4; ++e) {
      int q = mt * 16 + lg * 4 + e;
      if (q < 65) {
        u16* op = o + (bs0 + q) * 256 + hp * 64 + hl * 32;
        op[lr] = f2b(oa[0][e]);
        op[16 + lr] = f2b(oa[1][e]);
      }
    }
  }
}

__global__ __launch_bounds__(256) void out_copy(const u16* __restrict__ x,
                                                float* __restrict__ out) {
  const int b = blockIdx.x, tid = threadIdx.x;
  out[(size_t)b * 256 + tid] = b2f(x[(size_t)b * 65 * 256 + tid]);
  float* out2 = out + (size_t)2048 * 256;
  for (int i = tid; i < 64 * 256; i += 256) {
    int s = i >> 8, c = i & 255;
    out2[((size_t)b * 64 + s) * 256 + c] = b2f(x[((size_t)b * 65 + 1 + s) * 256 + c]);
  }
}

// =====================================================================

extern "C" void kernel_launch(void* const* d_in, const int* in_sizes, int n_in,
                              void* d_out, int out_size, void* d_ws, size_t ws_size,
                              hipStream_t stream) {
  (void)in_sizes; (void)n_in; (void)out_size;
  const float* msgs      = (const float*)d_in[0];
  const float* momenta   = (const float*)d_in[1];
  const float* edge_vec  = (const float*)d_in[2];
  const float* edge_dist = (const float*)d_in[3];
  const float* cutoff    = (const float*)d_in[4];
  const int* ein = (const int*)d_in[6];
  const int* enb = (const int*)d_in[7];
  const float* edge_w     = (const float*)d_in[8];
  const float* edge_b     = (const float*)d_in[9];
  const float* node_table = (const float*)d_in[10];
  const float* mom_w      = (const float*)d_in[11];
  const float* mom_b      = (const float*)d_in[12];
  const float* ncw        = (const float*)d_in[13];
  const float* ncb        = (const float*)d_in[14];
  const float* nbr_table  = (const float*)d_in[15];
  const float* cw1        = (const float*)d_in[16];
  const float* cb1        = (const float*)d_in[17];
  const float* cw2        = (const float*)d_in[18];
  const float* cb2        = (const float*)d_in[19];
  const float* qkv_w      = (const float*)d_in[20];
  const float* qkv_b      = (const float*)d_in[21];
  const float* aow        = (const float*)d_in[22];
  const float* aob        = (const float*)d_in[23];
  const float* ln1g       = (const float*)d_in[24];
  const float* ln1b       = (const float*)d_in[25];
  const float* fw1        = (const float*)d_in[26];
  const float* fb1        = (const float*)d_in[27];
  const float* fw2        = (const float*)d_in[28];
  const float* fb2        = (const float*)d_in[29];
  const float* ln2g       = (const float*)d_in[30];
  const float* ln2b       = (const float*)d_in[31];

  u16* ws = (u16*)d_ws;
  u16* cw1t  = ws + CW1T_OFF;
  u16* cw2t  = ws + CW2T_OFF;
  u16* qkvwt = ws + QKVWT_OFF;
  u16* aowt  = ws + AOWT_OFF;
  u16* fw1t  = ws + FW1T_OFF;
  u16* fw2t  = ws + FW2T_OFF;

  wconv<<<dim3((768 * 256 + 255) / 256, 1), 256, 0, stream>>>(cw1, cw1t, 768, 256);
  wconv<<<dim3((256 * 256 + 255) / 256, 1), 256, 0, stream>>>(cw2, cw2t, 256, 256);
  wconv<<<dim3((256 * 768 + 255) / 256, 3), 256, 0, stream>>>(qkv_w, qkvwt, 256, 768);
  wconv<<<dim3((256 * 256 + 255) / 256, 3), 256, 0, stream>>>(aow, aowt, 256, 256);
  wconv<<<dim3((256 * 1024 + 255) / 256, 3), 256, 0, stream>>>(fw1, fw1t, 256, 1024);
  wconv<<<dim3((1024 * 256 + 255) / 256, 3), 256, 0, stream>>>(fw2, fw2t, 1024, 256);

  u16* x    = (u16*)((char*)d_ws + X_OFF);
  u16* oslt = (u16*)((char*)d_ws + OSLOT_OFF);
  u16* big  = (u16*)((char*)d_ws + BIG_OFF);

  embed_k<<<2048, 512, 0, stream>>>(msgs, edge_vec, edge_dist, enb, edge_w,
                                    edge_b, nbr_table, big);
  gemm_bt<131072, 256, 768, 2><<<1024, 512, 0, stream>>>(big, cw1t, cb1, oslt);
  gemm_bt<131072, 256, 256, 3><<<1024, 512, 0, stream>>>(oslt, cw2t, cb2, x);
  node_row<<<2048, 256, 0, stream>>>(momenta, ein, node_table, mom_w, mom_b,
                                     ncw, ncb, x);
  for (int l = 0; l < 3; ++l) {
    gemm_bt<133120, 768, 256, 1><<<3120, 512, 0, stream>>>(
        x, qkvwt + (size_t)l * 196608, qkv_b + l * 768, big);
    attn_k2<<<dim3(2048, 4), 256, 0, stream>>>(big, cutoff, oslt);
    gemm_bt<133120, 256, 256, 0><<<1040, 512, 0, stream>>>(
        oslt, aowt + (size_t)l * 65536, aob, big);
    resln<<<2048, 256, 0, stream>>>(x, big, aob + l * 256, ln1g + l * 256,
                                    ln1b + l * 256);
    ffn_fused<<<2080, 256, 0, stream>>>(
        x, fw1t + (size_t)l * 262144, fb1 + l * 1024,
        fw2t + (size_t)l * 262144, oslt);
    resln<<<2048, 256, 0, stream>>>(x, oslt, fb2 + l * 256, ln2g + l * 256,
                                    ln2b + l * 256);
  }
  out_copy<<<2048, 256, 0, stream>>>(x, (float*)d_out);
}

// Round 13
// 2052.940 us; speedup vs baseline: 1.0908x; 1.0908x over previous
//
#include <hip/hip_runtime.h>
#include <hip/hip_bf16.h>

#define NT 512
typedef unsigned short u16;
typedef short s16x8 __attribute__((ext_vector_type(8)));
typedef float f32x4 __attribute__((ext_vector_type(4)));

constexpr int B_ = 2048, N_ = 64, S_ = 65, D_ = 256, L_ = 3;

// ---- workspace layout ----
constexpr size_t CW1T_OFF = 0;              // [256][768]
constexpr size_t CW2T_OFF = 196608;         // [256][256]
constexpr size_t QKVWT_OFF = 262144;        // [3][768][256]
constexpr size_t AOWT_OFF = 851968;         // [3][256][256]
constexpr size_t FW1T_OFF = 1048576;        // [3][1024][256]
constexpr size_t FW2T_OFF = 1835008;        // [3][256][1024]
constexpr size_t WS_W_BYTES = 5242880;
constexpr size_t X_OFF     = WS_W_BYTES;               // x bf16 [133120][256]
constexpr size_t OSLOT_OFF = X_OFF + 68157440;         // G1 / o / delta2
constexpr size_t BIG_OFF   = OSLOT_OFF + 68157440;     // T / qkv / delta / h1
constexpr size_t WS_NEEDED = BIG_OFF + 272629760;      // ≈ 395 MB

#define MFMA16(a, b, c) __builtin_amdgcn_mfma_f32_16x16x32_bf16(a, b, c, 0, 0, 0)

typedef __attribute__((address_space(3))) unsigned int lds_uint;
typedef __attribute__((address_space(1))) const unsigned int glb_uint;
// async global->LDS copy: lane l writes lds + l*16B; lds base must be
// wave-uniform; global address is per-lane.
__device__ __forceinline__ void gload_lds16(const void* g, void* l) {
  __builtin_amdgcn_global_load_lds((glb_uint*)g, (lds_uint*)l, 16, 0, 0);
}

__device__ __forceinline__ u16 f2b(float f) {
  __hip_bfloat16 h = __float2bfloat16(f);
  return *reinterpret_cast<u16*>(&h);
}
__device__ __forceinline__ float b2f(u16 u) { return __uint_as_float(((unsigned)u) << 16); }
__device__ __forceinline__ float sigm(float x) { return 1.0f / (1.0f + __expf(-x)); }

__device__ __forceinline__ float wave_sum(float v) {
#pragma unroll
  for (int o = 32; o > 0; o >>= 1) v += __shfl_xor(v, o);
  return v;
}
__device__ __forceinline__ float wave_max(float v) {
#pragma unroll
  for (int o = 32; o > 0; o >>= 1) v = fmaxf(v, __shfl_xor(v, o));
  return v;
}
__device__ __forceinline__ void unpack8(const u16* p, float* f) {
  uint4 u = *reinterpret_cast<const uint4*>(p);
  f[0] = __uint_as_float(u.x << 16); f[1] = __uint_as_float(u.x & 0xffff0000u);
  f[2] = __uint_as_float(u.y << 16); f[3] = __uint_as_float(u.y & 0xffff0000u);
  f[4] = __uint_as_float(u.z << 16); f[5] = __uint_as_float(u.z & 0xffff0000u);
  f[6] = __uint_as_float(u.w << 16); f[7] = __uint_as_float(u.w & 0xffff0000u);
}

// transpose-convert: src [K][N] f32 -> dst [N][K] bf16 (batched over blockIdx.y)
__global__ void wconv(const float* __restrict__ src, u16* __restrict__ dst, int K, int N) {
  const size_t bo = (size_t)blockIdx.y * K * N;
  int idx = blockIdx.x * 256 + threadIdx.x;
  if (idx >= K * N) return;
  int n = idx / K, k = idx - n * K;
  dst[bo + idx] = f2b(src[bo + (size_t)k * N + n]);
}

// =====================================================================
// Phase-split path (round-11 proven components; round-13: ffn_fused
// reverted — it was latency-bound at 2 blocks/CU and regressed)
// =====================================================================

// C[m][n] = sum_k A[m][k]*Bt[n][k].  128x256 tile, 8 waves (2x4 wave grid,
// each wave 64x64 / acc[4][4]).  global_load_lds staging, XCD swizzle.
// EPI: 0 plain; 1 +bias; 2 silu(+bias); 3 +bias, strided x-row write.
template <int M, int N, int K, int EPI>
__global__ __launch_bounds__(512, 4) void gemm_bt(
    const u16* __restrict__ A, const u16* __restrict__ Bt,
    const float* __restrict__ bias, u16* __restrict__ C) {
  constexpr int MT_ = M / 128, NT_ = N / 256;
  constexpr int CHUNK = (MT_ * NT_) / 8;   // all grids divisible by 8
  const int logical = (blockIdx.x % 8) * CHUNK + blockIdx.x / 8;
  const int mt = logical / NT_, nt = logical % NT_;
  const int m0 = mt * 128, n0 = nt * 256;
  const int tid = threadIdx.x, lane = tid & 63, w = tid >> 6;
  const int lr = lane & 15, lg = lane >> 4;
  const int wr = w >> 2, wc = w & 3;   // wave grid: 2 row-tiles x 4 col-tiles

  __shared__ __align__(16) u16 sm[64 * 264];  // K: As[4096]|Bs[8192]; epi: Cs[64][264]
  u16* As = sm;          // [128][32]
  u16* Bs = sm + 4096;   // [256][32]
  f32x4 acc[4][4] = {};

  const int arow = w * 16 + (lane >> 2);
  const int brow = w * 32 + (lane >> 2);
  const int scol = (lane & 3) * 8;

  for (int k0 = 0; k0 < K; k0 += 32) {
    __syncthreads();
    gload_lds16(&A[(size_t)(m0 + arow) * K + k0 + scol],       &As[(w * 16) * 32]);
    gload_lds16(&Bt[(size_t)(n0 + brow) * K + k0 + scol],      &Bs[(w * 32) * 32]);
    gload_lds16(&Bt[(size_t)(n0 + brow + 16) * K + k0 + scol], &Bs[(w * 32 + 16) * 32]);
    __syncthreads();
    s16x8 af[4], bf[4];
#pragma unroll
    for (int i = 0; i < 4; ++i)
      af[i] = *(const s16x8*)&As[(wr * 64 + i * 16 + lr) * 32 + lg * 8];
#pragma unroll
    for (int j = 0; j < 4; ++j)
      bf[j] = *(const s16x8*)&Bs[(wc * 64 + j * 16 + lr) * 32 + lg * 8];
#pragma unroll
    for (int i = 0; i < 4; ++i)
#pragma unroll
      for (int j = 0; j < 4; ++j)
        acc[i][j] = MFMA16(af[i], bf[j], acc[i][j]);
  }

#pragma unroll
  for (int h = 0; h < 2; ++h) {
    __syncthreads();
    if (wr == h) {
#pragma unroll
      for (int j = 0; j < 4; ++j) {
        const int nl = wc * 64 + j * 16 + lr;
        const float bb = (EPI == 0) ? 0.0f : bias[n0 + nl];
#pragma unroll
        for (int i = 0; i < 4; ++i)
#pragma unroll
          for (int e = 0; e < 4; ++e) {
            float v = acc[i][j][e] + bb;
            if (EPI == 2) v = v * sigm(v);
            sm[(i * 16 + lg * 4 + e) * 264 + nl] = f2b(v);
          }
      }
    }
    __syncthreads();
    const int mbase = m0 + h * 64;
    const size_t gbase = (EPI == 3) ? (size_t)((mbase >> 6) * 65 + 1) : (size_t)mbase;
    for (int idx = tid; idx < 64 * 32; idx += 512) {
      int row = idx >> 5, c8 = idx & 31;
      *(uint4*)&C[(gbase + row) * N + n0 + c8 * 8] = *(const uint4*)&sm[row * 264 + c8 * 8];
    }
  }
}

// x = LN(x + delta + cbias) row-wise; 133120 rows  [round-4 proven version]
__global__ __launch_bounds__(256) void resln(
    u16* __restrict__ x, const u16* __restrict__ delta,
    const float* __restrict__ cbias, const float* __restrict__ g,
    const float* __restrict__ bb) {
  const int lane = threadIdx.x & 63, w = threadIdx.x >> 6;
  const float4 gv = *(const float4*)&g[lane * 4];
  const float4 bv = *(const float4*)&bb[lane * 4];
  const float4 cb = *(const float4*)&cbias[lane * 4];
  for (int r = blockIdx.x * 4 + w; r < 133120; r += 8192) {
    uint2 xu = *(const uint2*)&x[(size_t)r * 256 + lane * 4];
    uint2 du = *(const uint2*)&delta[(size_t)r * 256 + lane * 4];
    float v0 = __uint_as_float(xu.x << 16) + __uint_as_float(du.x << 16) + cb.x;
    float v1 = __uint_as_float(xu.x & 0xffff0000u) + __uint_as_float(du.x & 0xffff0000u) + cb.y;
    float v2 = __uint_as_float(xu.y << 16) + __uint_as_float(du.y << 16) + cb.z;
    float v3 = __uint_as_float(xu.y & 0xffff0000u) + __uint_as_float(du.y & 0xffff0000u) + cb.w;
    float mean = wave_sum(v0 + v1 + v2 + v3) * (1.0f / 256.0f);
    float d0 = v0 - mean, d1 = v1 - mean, d2 = v2 - mean, d3 = v3 - mean;
    float var = wave_sum(d0 * d0 + d1 * d1 + d2 * d2 + d3 * d3) * (1.0f / 256.0f);
    float rs = rsqrtf(var + 1e-5f);
    uint2 p;
    p.x = f2b(d0 * rs * gv.x + bv.x) | ((unsigned)f2b(d1 * rs * gv.y + bv.y) << 16);
    p.y = f2b(d2 * rs * gv.z + bv.z) | ((unsigned)f2b(d3 * rs * gv.w + bv.w) << 16);
    *(uint2*)&x[(size_t)r * 256 + lane * 4] = p;
  }
}

// Final-layer variant: same LN math as resln, but writes the f32 outputs
// directly in the harness layout (out0 [2048][256] = s==0 rows; out1
// [2048][64][256] = s>=1 rows), replacing resln+out_copy.  x not written
// (nothing reads it afterwards).
__global__ __launch_bounds__(256) void resln_out(
    const u16* __restrict__ x, const u16* __restrict__ delta,
    const float* __restrict__ cbias, const float* __restrict__ g,
    const float* __restrict__ bb, float* __restrict__ out) {
  const int lane = threadIdx.x & 63, w = threadIdx.x >> 6;
  const float4 gv = *(const float4*)&g[lane * 4];
  const float4 bv = *(const float4*)&bb[lane * 4];
  const float4 cb = *(const float4*)&cbias[lane * 4];
  float* out2 = out + (size_t)2048 * 256;
  for (int r = blockIdx.x * 4 + w; r < 133120; r += 8192) {
    uint2 xu = *(const uint2*)&x[(size_t)r * 256 + lane * 4];
    uint2 du = *(const uint2*)&delta[(size_t)r * 256 + lane * 4];
    float v0 = __uint_as_float(xu.x << 16) + __uint_as_float(du.x << 16) + cb.x;
    float v1 = __uint_as_float(xu.x & 0xffff0000u) + __uint_as_float(du.x & 0xffff0000u) + cb.y;
    float v2 = __uint_as_float(xu.y << 16) + __uint_as_float(du.y << 16) + cb.z;
    float v3 = __uint_as_float(xu.y & 0xffff0000u) + __uint_as_float(du.y & 0xffff0000u) + cb.w;
    float mean = wave_sum(v0 + v1 + v2 + v3) * (1.0f / 256.0f);
    float d0 = v0 - mean, d1 = v1 - mean, d2 = v2 - mean, d3 = v3 - mean;
    float var = wave_sum(d0 * d0 + d1 * d1 + d2 * d2 + d3 * d3) * (1.0f / 256.0f);
    float rs = rsqrtf(var + 1e-5f);
    float4 y;
    y.x = d0 * rs * gv.x + bv.x;
    y.y = d1 * rs * gv.y + bv.y;
    y.z = d2 * rs * gv.z + bv.z;
    y.w = d3 * rs * gv.w + bv.w;
    const int b = r / 65, s = r - b * 65;
    float* dst = (s == 0) ? (out + (size_t)b * 256)
                          : (out2 + ((size_t)b * 64 + (s - 1)) * 256);
    *(float4*)&dst[lane * 4] = y;
  }
}

// Build T [131072][768] bf16: concat(edge-proj, nbr_table gather, msgs)
__global__ __launch_bounds__(512) void embed_k(
    const float* __restrict__ msgs, const float* __restrict__ edge_vec,
    const float* __restrict__ edge_dist, const int* __restrict__ enb,
    const float* __restrict__ edge_w, const float* __restrict__ edge_b,
    const float* __restrict__ nbr_table, u16* __restrict__ T) {
  const int r0 = blockIdx.x * 64, tid = threadIdx.x;
  __shared__ float tv[64][4];
  if (tid < 256) {
    int r = tid >> 2, j = tid & 3;
    tv[r][j] = (j < 3) ? edge_vec[(size_t)(r0 + r) * 3 + j] : edge_dist[r0 + r];
  }
  __syncthreads();
  for (int idx = tid; idx < 64 * 192; idx += 512) {
    int r = idx / 192, c4 = (idx % 192) * 4;
    size_t gn = (size_t)r0 + r;
    float4 v;
    if (c4 < 256) {
      float t0 = tv[r][0], t1 = tv[r][1], t2 = tv[r][2], t3 = tv[r][3];
      const float4 w0 = *(const float4*)&edge_w[c4];
      const float4 w1 = *(const float4*)&edge_w[256 + c4];
      const float4 w2 = *(const float4*)&edge_w[512 + c4];
      const float4 w3 = *(const float4*)&edge_w[768 + c4];
      const float4 eb4 = *(const float4*)&edge_b[c4];
      v.x = t0 * w0.x + t1 * w1.x + t2 * w2.x + t3 * w3.x + eb4.x;
      v.y = t0 * w0.y + t1 * w1.y + t2 * w2.y + t3 * w3.y + eb4.y;
      v.z = t0 * w0.z + t1 * w1.z + t2 * w2.z + t3 * w3.z + eb4.z;
      v.w = t0 * w0.w + t1 * w1.w + t2 * w2.w + t3 * w3.w + eb4.w;
    } else if (c4 < 512) {
      v = *(const float4*)&nbr_table[(size_t)enb[gn] * 256 + (c4 - 256)];
    } else {
      v = *(const float4*)&msgs[gn * 256 + (c4 - 512)];
    }
    uint2 p;
    p.x = f2b(v.x) | ((unsigned)f2b(v.y) << 16);
    p.y = f2b(v.z) | ((unsigned)f2b(v.w) << 16);
    *(uint2*)&T[gn * 768 + c4] = p;
  }
}

// node row s=0 per batch
__global__ __launch_bounds__(256) void node_row(
    const float* __restrict__ momenta, const int* __restrict__ ein,
    const float* __restrict__ node_table, const float* __restrict__ mom_w,
    const float* __restrict__ mom_b, const float* __restrict__ ncw,
    const float* __restrict__ ncb, u16* __restrict__ x) {
  const int b = blockIdx.x, tid = threadIdx.x;
  __shared__ float cvec[512];
  cvec[tid] = node_table[(size_t)ein[b] * 256 + tid];
  float m0 = momenta[b * 3], m1 = momenta[b * 3 + 1], m2 = momenta[b * 3 + 2];
  cvec[256 + tid] = m0 * mom_w[tid] + m1 * mom_w[256 + tid] + m2 * mom_w[512 + tid] + mom_b[tid];
  __syncthreads();
  float acc = 0.0f;
  for (int k = 0; k < 512; k += 4) {
    const float4 cv = *(const float4*)&cvec[k];
    acc += cv.x * ncw[(k + 0) * 256 + tid] + cv.y * ncw[(k + 1) * 256 + tid] +
           cv.z * ncw[(k + 2) * 256 + tid] + cv.w * ncw[(k + 3) * 256 + tid];
  }
  x[(size_t)b * 65 * 256 + tid] = f2b(acc + ncb[tid]);
}

// MFMA attention: block = (b, head-pair), 4 waves, 2 waves per head.
__global__ __launch_bounds__(256, 2) void attn_k2(
    const u16* __restrict__ qkv, const float* __restrict__ cutoff,
    u16* __restrict__ o) {
  const int b = blockIdx.x, hp = blockIdx.y;
  const int tid = threadIdx.x, lane = tid & 63, w = tid >> 6;
  const int lr = lane & 15, lg = lane >> 4;
  const int hl = w >> 1, wp = w & 1;
  const size_t bs0 = (size_t)b * 65;

  __shared__ __align__(16) u16 Qs[2][80][40];
  __shared__ __align__(16) u16 Ks[2][80][40];
  __shared__ __align__(16) u16 Vt[2][32][104];
  __shared__ __align__(16) u16 Ps[2][80][104];
  __shared__ float bias_s[80];

  if (tid < 80) {
    float bv;
    if (tid == 0) bv = 0.0f;
    else if (tid < 65) {
      float cf = cutoff[b * 64 + tid - 1];
      bv = (cf > 0.0f) ? logf(fmaxf(cf, 1e-30f)) : -1e9f;
    } else bv = -1e9f;
    bias_s[tid] = bv;
  }
  for (int idx = tid; idx < 2 * 80 * 4; idx += 256) {
    int h2 = idx / 320, rem = idx - h2 * 320;
    int q = rem >> 2, j = rem & 3;
    *(uint2*)&Ps[h2][q][80 + j * 4] = make_uint2(0, 0);
  }
  for (int idx = tid; idx < 2 * 32 * 4; idx += 256) {
    int h2 = idx / 128, rem = idx - h2 * 128;
    int d = rem >> 2, j = rem & 3;
    *(uint2*)&Vt[h2][d][80 + j * 4] = make_uint2(0, 0);
  }
  for (int idx = tid; idx < 2 * 80 * 8; idx += 256) {
    int h2 = idx / 640, rem = idx - h2 * 640;
    int s = rem >> 3, c4 = (rem & 7) << 2;
    uint2 vq = make_uint2(0, 0), vk = vq, vv = vq;
    if (s < 65) {
      const u16* base = qkv + (bs0 + s) * 768 + (hp * 2 + h2) * 32 + c4;
      vq = *(const uint2*)(base);
      vk = *(const uint2*)(base + 256);
      vv = *(const uint2*)(base + 512);
    }
    *(uint2*)&Qs[h2][s][c4] = vq;
    *(uint2*)&Ks[h2][s][c4] = vk;
    Vt[h2][c4 + 0][s] = (u16)(vv.x & 0xffffu);
    Vt[h2][c4 + 1][s] = (u16)(vv.x >> 16);
    Vt[h2][c4 + 2][s] = (u16)(vv.y & 0xffffu);
    Vt[h2][c4 + 3][s] = (u16)(vv.y >> 16);
  }
  __syncthreads();

  const int nt0 = wp ? 3 : 0, nt1 = wp ? 5 : 3;
  for (int nt = nt0; nt < nt1; ++nt) {
    s16x8 bq = *(const s16x8*)&Qs[hl][nt * 16 + lr][lg * 8];
    f32x4 sacc[5];
#pragma unroll
    for (int mt = 0; mt < 5; ++mt) {
      s16x8 ak = *(const s16x8*)&Ks[hl][mt * 16 + lr][lg * 8];
      f32x4 z = {0.f, 0.f, 0.f, 0.f};
      sacc[mt] = MFMA16(ak, bq, z);
    }
    float pv[5][4];
    float cmax = -3e38f;
#pragma unroll
    for (int mt = 0; mt < 5; ++mt)
#pragma unroll
      for (int e = 0; e < 4; ++e) {
        float v = sacc[mt][e] * 0.17677669529663687f + bias_s[mt * 16 + lg * 4 + e];
        pv[mt][e] = v;
        cmax = fmaxf(cmax, v);
      }
    cmax = fmaxf(cmax, __shfl_xor(cmax, 16));
    cmax = fmaxf(cmax, __shfl_xor(cmax, 32));
    float csum = 0.f;
#pragma unroll
    for (int mt = 0; mt < 5; ++mt)
#pragma unroll
      for (int e = 0; e < 4; ++e) {
        float p = __expf(pv[mt][e] - cmax);
        pv[mt][e] = p;
        csum += p;
      }
    csum += __shfl_xor(csum, 16);
    csum += __shfl_xor(csum, 32);
    float rinv = 1.0f / csum;
    const int q = nt * 16 + lr;
#pragma unroll
    for (int mt = 0; mt < 5; ++mt) {
      uint2 pk;
      pk.x = (unsigned)f2b(pv[mt][0] * rinv) | ((unsigned)f2b(pv[mt][1] * rinv) << 16);
      pk.y = (unsigned)f2b(pv[mt][2] * rinv) | ((unsigned)f2b(pv[mt][3] * rinv) << 16);
      *(uint2*)&Ps[hl][q][mt * 16 + lg * 4] = pk;
    }
  }
  __syncthreads();

  s16x8 vb[2][3];
#pragma unroll
  for (int d2 = 0; d2 < 2; ++d2)
#pragma unroll
    for (int ks = 0; ks < 3; ++ks)
      vb[d2][ks] = *(const s16x8*)&Vt[hl][d2 * 16 + lr][ks * 32 + lg * 8];
  const int mt0 = wp ? 3 : 0, mt1 = wp ? 5 : 3;
  for (int mt = mt0; mt < mt1; ++mt) {
    f32x4 oa[2] = {};
#pragma unroll
    for (int ks = 0; ks < 3; ++ks) {
      s16x8 pa = *(const s16x8*)&Ps[hl][mt * 16 + lr][ks * 32 + lg * 8];
#pragma unroll
      for (int d2 = 0; d2 < 2; ++d2) oa[d2] = MFMA16(pa, vb[d2][ks], oa[d2]);
    }
#pragma unroll
    for (int e = 0; e < 4; ++e) {
      int q = mt * 16 + lg * 4 + e;
      if (q < 65) {
        u16* op = o + (bs0 + q) * 256 + hp * 64 + hl * 32;
        op[lr] = f2b(oa[0][e]);
        op[16 + lr] = f2b(oa[1][e]);
      }
    }
  }
}

// =====================================================================

extern "C" void kernel_launch(void* const* d_in, const int* in_sizes, int n_in,
                              void* d_out, int out_size, void* d_ws, size_t ws_size,
                              hipStream_t stream) {
  (void)in_sizes; (void)n_in; (void)out_size; (void)ws_size;
  const float* msgs      = (const float*)d_in[0];
  const float* momenta   = (const float*)d_in[1];
  const float* edge_vec  = (const float*)d_in[2];
  const float* edge_dist = (const float*)d_in[3];
  const float* cutoff    = (const float*)d_in[4];
  const int* ein = (const int*)d_in[6];
  const int* enb = (const int*)d_in[7];
  const float* edge_w     = (const float*)d_in[8];
  const float* edge_b     = (const float*)d_in[9];
  const float* node_table = (const float*)d_in[10];
  const float* mom_w      = (const float*)d_in[11];
  const float* mom_b      = (const float*)d_in[12];
  const float* ncw        = (const float*)d_in[13];
  const float* ncb        = (const float*)d_in[14];
  const float* nbr_table  = (const float*)d_in[15];
  const float* cw1        = (const float*)d_in[16];
  const float* cb1        = (const float*)d_in[17];
  const float* cw2        = (const float*)d_in[18];
  const float* cb2        = (const float*)d_in[19];
  const float* qkv_w      = (const float*)d_in[20];
  const float* qkv_b      = (const float*)d_in[21];
  const float* aow        = (const float*)d_in[22];
  const float* aob        = (const float*)d_in[23];
  const float* ln1g       = (const float*)d_in[24];
  const float* ln1b       = (const float*)d_in[25];
  const float* fw1        = (const float*)d_in[26];
  const float* fb1        = (const float*)d_in[27];
  const float* fw2        = (const float*)d_in[28];
  const float* fb2        = (const float*)d_in[29];
  const float* ln2g       = (const float*)d_in[30];
  const float* ln2b       = (const float*)d_in[31];

  u16* ws = (u16*)d_ws;
  u16* cw1t  = ws + CW1T_OFF;
  u16* cw2t  = ws + CW2T_OFF;
  u16* qkvwt = ws + QKVWT_OFF;
  u16* aowt  = ws + AOWT_OFF;
  u16* fw1t  = ws + FW1T_OFF;
  u16* fw2t  = ws + FW2T_OFF;

  wconv<<<dim3((768 * 256 + 255) / 256, 1), 256, 0, stream>>>(cw1, cw1t, 768, 256);
  wconv<<<dim3((256 * 256 + 255) / 256, 1), 256, 0, stream>>>(cw2, cw2t, 256, 256);
  wconv<<<dim3((256 * 768 + 255) / 256, 3), 256, 0, stream>>>(qkv_w, qkvwt, 256, 768);
  wconv<<<dim3((256 * 256 + 255) / 256, 3), 256, 0, stream>>>(aow, aowt, 256, 256);
  wconv<<<dim3((256 * 1024 + 255) / 256, 3), 256, 0, stream>>>(fw1, fw1t, 256, 1024);
  wconv<<<dim3((1024 * 256 + 255) / 256, 3), 256, 0, stream>>>(fw2, fw2t, 1024, 256);

  u16* x    = (u16*)((char*)d_ws + X_OFF);
  u16* oslt = (u16*)((char*)d_ws + OSLOT_OFF);
  u16* big  = (u16*)((char*)d_ws + BIG_OFF);

  embed_k<<<2048, 512, 0, stream>>>(msgs, edge_vec, edge_dist, enb, edge_w,
                                    edge_b, nbr_table, big);
  gemm_bt<131072, 256, 768, 2><<<1024, 512, 0, stream>>>(big, cw1t, cb1, oslt);
  gemm_bt<131072, 256, 256, 3><<<1024, 512, 0, stream>>>(oslt, cw2t, cb2, x);
  node_row<<<2048, 256, 0, stream>>>(momenta, ein, node_table, mom_w, mom_b,
                                     ncw, ncb, x);
  for (int l = 0; l < 3; ++l) {
    gemm_bt<133120, 768, 256, 1><<<3120, 512, 0, stream>>>(
        x, qkvwt + (size_t)l * 196608, qkv_b + l * 768, big);
    attn_k2<<<dim3(2048, 4), 256, 0, stream>>>(big, cutoff, oslt);
    gemm_bt<133120, 256, 256, 0><<<1040, 512, 0, stream>>>(
        oslt, aowt + (size_t)l * 65536, aob, big);
    resln<<<2048, 256, 0, stream>>>(x, big, aob + l * 256, ln1g + l * 256,
                                    ln1b + l * 256);
    gemm_bt<133120, 1024, 256, 2><<<4160, 512, 0, stream>>>(
        x, fw1t + (size_t)l * 262144, fb1 + l * 1024, big);
    gemm_bt<133120, 256, 1024, 0><<<1040, 512, 0, stream>>>(
        big, fw2t + (size_t)l * 262144, fb2, oslt);
    if (l < 2) {
      resln<<<2048, 256, 0, stream>>>(x, oslt, fb2 + l * 256, ln2g + l * 256,
                                      ln2b + l * 256);
    } else {
      resln_out<<<2048, 256, 0, stream>>>(x, oslt, fb2 + l * 256,
                                          ln2g + l * 256, ln2b + l * 256,
                                          (float*)d_out);
    }
  }
}

// Round 14
// 1975.880 us; speedup vs baseline: 1.1333x; 1.0390x over previous
//
#include <hip/hip_runtime.h>
#include <hip/hip_bf16.h>

#define NT 512
typedef unsigned short u16;
typedef short s16x8 __attribute__((ext_vector_type(8)));
typedef float f32x4 __attribute__((ext_vector_type(4)));

constexpr int B_ = 2048, N_ = 64, S_ = 65, D_ = 256, L_ = 3;

// ---- workspace layout ----
constexpr size_t CW1T_OFF = 0;              // [256][768]
constexpr size_t CW2T_OFF = 196608;         // [256][256]
constexpr size_t QKVWT_OFF = 262144;        // [3][768][256]
constexpr size_t AOWT_OFF = 851968;         // [3][256][256]
constexpr size_t FW1T_OFF = 1048576;        // [3][1024][256]
constexpr size_t FW2T_OFF = 1835008;        // [3][256][1024]
constexpr size_t WS_W_BYTES = 5242880;
constexpr size_t X_OFF     = WS_W_BYTES;               // x bf16 [133120][256]
constexpr size_t OSLOT_OFF = X_OFF + 68157440;         // G1 / o / delta2
constexpr size_t BIG_OFF   = OSLOT_OFF + 68157440;     // T / qkv / delta / h1
constexpr size_t WS_NEEDED = BIG_OFF + 272629760;      // ≈ 395 MB

#define MFMA16(a, b, c) __builtin_amdgcn_mfma_f32_16x16x32_bf16(a, b, c, 0, 0, 0)

typedef __attribute__((address_space(3))) unsigned int lds_uint;
typedef __attribute__((address_space(1))) const unsigned int glb_uint;
// async global->LDS copy: lane l writes lds + l*16B; lds base must be
// wave-uniform; global address is per-lane.
__device__ __forceinline__ void gload_lds16(const void* g, void* l) {
  __builtin_amdgcn_global_load_lds((glb_uint*)g, (lds_uint*)l, 16, 0, 0);
}

__device__ __forceinline__ u16 f2b(float f) {
  __hip_bfloat16 h = __float2bfloat16(f);
  return *reinterpret_cast<u16*>(&h);
}
__device__ __forceinline__ float b2f(u16 u) { return __uint_as_float(((unsigned)u) << 16); }
__device__ __forceinline__ float sigm(float x) { return 1.0f / (1.0f + __expf(-x)); }

__device__ __forceinline__ float wave_sum(float v) {
#pragma unroll
  for (int o = 32; o > 0; o >>= 1) v += __shfl_xor(v, o);
  return v;
}
__device__ __forceinline__ float wave_max(float v) {
#pragma unroll
  for (int o = 32; o > 0; o >>= 1) v = fmaxf(v, __shfl_xor(v, o));
  return v;
}
__device__ __forceinline__ void unpack8(const u16* p, float* f) {
  uint4 u = *reinterpret_cast<const uint4*>(p);
  f[0] = __uint_as_float(u.x << 16); f[1] = __uint_as_float(u.x & 0xffff0000u);
  f[2] = __uint_as_float(u.y << 16); f[3] = __uint_as_float(u.y & 0xffff0000u);
  f[4] = __uint_as_float(u.z << 16); f[5] = __uint_as_float(u.z & 0xffff0000u);
  f[6] = __uint_as_float(u.w << 16); f[7] = __uint_as_float(u.w & 0xffff0000u);
}

// transpose-convert: src [K][N] f32 -> dst [N][K] bf16 (batched over blockIdx.y)
__global__ void wconv(const float* __restrict__ src, u16* __restrict__ dst, int K, int N) {
  const size_t bo = (size_t)blockIdx.y * K * N;
  int idx = blockIdx.x * 256 + threadIdx.x;
  if (idx >= K * N) return;
  int n = idx / K, k = idx - n * K;
  dst[bo + idx] = f2b(src[bo + (size_t)k * N + n]);
}

// =====================================================================
// Phase-split path
// =====================================================================

// C[m][n] = sum_k A[m][k]*Bt[n][k].  128x256 tile, 8 waves (2x4 wave grid,
// each wave 64x64 / acc[4][4]).  Round-14: 2-phase double-buffered K-loop
// (guide T3 minimum recipe): STAGE(t+1) issued BEFORE ds_read+MFMA of tile
// t, ONE barrier per tile -> load latency hides under compute (was: issue
// + immediate vmcnt(0) drain each iter; 8 iters x ~300cy exposed stall).
// LDS 48 KB (2 x 24 KB buffers) -> 3 blocks/CU; epilogue reuses buffer 0.
// EPI: 0 plain; 1 +bias; 2 silu(+bias); 3 +bias, strided x-row write.
template <int M, int N, int K, int EPI>
__global__ __launch_bounds__(512, 4) void gemm_bt(
    const u16* __restrict__ A, const u16* __restrict__ Bt,
    const float* __restrict__ bias, u16* __restrict__ C) {
  constexpr int MT_ = M / 128, NT_ = N / 256;
  constexpr int CHUNK = (MT_ * NT_) / 8;   // all grids divisible by 8
  const int logical = (blockIdx.x % 8) * CHUNK + blockIdx.x / 8;
  const int mt = logical / NT_, nt = logical % NT_;
  const int m0 = mt * 128, n0 = nt * 256;
  const int tid = threadIdx.x, lane = tid & 63, w = tid >> 6;
  const int lr = lane & 15, lg = lane >> 4;
  const int wr = w >> 2, wc = w & 3;   // wave grid: 2 row-tiles x 4 col-tiles

  // buf b: As[128][32] at b*12288, Bs[256][32] at b*12288+4096 (u16 offsets)
  __shared__ __align__(16) u16 sm[24576];   // 49152 B; epi Cs[64][264] reuses
  f32x4 acc[4][4] = {};

  const int arow = w * 16 + (lane >> 2);
  const int brow = w * 32 + (lane >> 2);
  const int scol = (lane & 3) * 8;

  // prologue: stage tile 0 into buf 0, drain, barrier
  {
    u16* As = sm;
    u16* Bs = sm + 4096;
    gload_lds16(&A[(size_t)(m0 + arow) * K + scol],       &As[(w * 16) * 32]);
    gload_lds16(&Bt[(size_t)(n0 + brow) * K + scol],      &Bs[(w * 32) * 32]);
    gload_lds16(&Bt[(size_t)(n0 + brow + 16) * K + scol], &Bs[(w * 32 + 16) * 32]);
  }
  __syncthreads();

  constexpr int NITER = K / 32;
  int cur = 0;
  for (int t = 0; t < NITER; ++t) {
    if (t + 1 < NITER) {  // issue next-tile loads first (stay in flight)
      const int k1 = (t + 1) * 32;
      u16* As = sm + (cur ^ 1) * 12288;
      u16* Bs = As + 4096;
      gload_lds16(&A[(size_t)(m0 + arow) * K + k1 + scol],       &As[(w * 16) * 32]);
      gload_lds16(&Bt[(size_t)(n0 + brow) * K + k1 + scol],      &Bs[(w * 32) * 32]);
      gload_lds16(&Bt[(size_t)(n0 + brow + 16) * K + k1 + scol], &Bs[(w * 32 + 16) * 32]);
    }
    const u16* Asc = sm + cur * 12288;
    const u16* Bsc = Asc + 4096;
    s16x8 af[4], bf[4];
#pragma unroll
    for (int i = 0; i < 4; ++i)
      af[i] = *(const s16x8*)&Asc[(wr * 64 + i * 16 + lr) * 32 + lg * 8];
#pragma unroll
    for (int j = 0; j < 4; ++j)
      bf[j] = *(const s16x8*)&Bsc[(wc * 64 + j * 16 + lr) * 32 + lg * 8];
#pragma unroll
    for (int i = 0; i < 4; ++i)
#pragma unroll
      for (int j = 0; j < 4; ++j)
        acc[i][j] = MFMA16(af[i], bf[j], acc[i][j]);
    __syncthreads();  // drains vmcnt(0): next tile staged; cur readers done
    cur ^= 1;
  }

  // epilogue: stage 64-row halves through LDS (Cs[64][264]), coalesced stores
#pragma unroll
  for (int h = 0; h < 2; ++h) {
    __syncthreads();
    if (wr == h) {
#pragma unroll
      for (int j = 0; j < 4; ++j) {
        const int nl = wc * 64 + j * 16 + lr;
        const float bb = (EPI == 0) ? 0.0f : bias[n0 + nl];
#pragma unroll
        for (int i = 0; i < 4; ++i)
#pragma unroll
          for (int e = 0; e < 4; ++e) {
            float v = acc[i][j][e] + bb;
            if (EPI == 2) v = v * sigm(v);
            sm[(i * 16 + lg * 4 + e) * 264 + nl] = f2b(v);
          }
      }
    }
    __syncthreads();
    const int mbase = m0 + h * 64;
    const size_t gbase = (EPI == 3) ? (size_t)((mbase >> 6) * 65 + 1) : (size_t)mbase;
    for (int idx = tid; idx < 64 * 32; idx += 512) {
      int row = idx >> 5, c8 = idx & 31;
      *(uint4*)&C[(gbase + row) * N + n0 + c8 * 8] = *(const uint4*)&sm[row * 264 + c8 * 8];
    }
  }
}

// x = LN(x + delta + cbias) row-wise; 133120 rows  [round-4 proven version]
__global__ __launch_bounds__(256) void resln(
    u16* __restrict__ x, const u16* __restrict__ delta,
    const float* __restrict__ cbias, const float* __restrict__ g,
    const float* __restrict__ bb) {
  const int lane = threadIdx.x & 63, w = threadIdx.x >> 6;
  const float4 gv = *(const float4*)&g[lane * 4];
  const float4 bv = *(const float4*)&bb[lane * 4];
  const float4 cb = *(const float4*)&cbias[lane * 4];
  for (int r = blockIdx.x * 4 + w; r < 133120; r += 8192) {
    uint2 xu = *(const uint2*)&x[(size_t)r * 256 + lane * 4];
    uint2 du = *(const uint2*)&delta[(size_t)r * 256 + lane * 4];
    float v0 = __uint_as_float(xu.x << 16) + __uint_as_float(du.x << 16) + cb.x;
    float v1 = __uint_as_float(xu.x & 0xffff0000u) + __uint_as_float(du.x & 0xffff0000u) + cb.y;
    float v2 = __uint_as_float(xu.y << 16) + __uint_as_float(du.y << 16) + cb.z;
    float v3 = __uint_as_float(xu.y & 0xffff0000u) + __uint_as_float(du.y & 0xffff0000u) + cb.w;
    float mean = wave_sum(v0 + v1 + v2 + v3) * (1.0f / 256.0f);
    float d0 = v0 - mean, d1 = v1 - mean, d2 = v2 - mean, d3 = v3 - mean;
    float var = wave_sum(d0 * d0 + d1 * d1 + d2 * d2 + d3 * d3) * (1.0f / 256.0f);
    float rs = rsqrtf(var + 1e-5f);
    uint2 p;
    p.x = f2b(d0 * rs * gv.x + bv.x) | ((unsigned)f2b(d1 * rs * gv.y + bv.y) << 16);
    p.y = f2b(d2 * rs * gv.z + bv.z) | ((unsigned)f2b(d3 * rs * gv.w + bv.w) << 16);
    *(uint2*)&x[(size_t)r * 256 + lane * 4] = p;
  }
}

// Final-layer variant: same LN math, writes f32 outputs directly in the
// harness layout (out0 = s==0 rows; out1 = s>=1 rows).  [round-13 proven]
__global__ __launch_bounds__(256) void resln_out(
    const u16* __restrict__ x, const u16* __restrict__ delta,
    const float* __restrict__ cbias, const float* __restrict__ g,
    const float* __restrict__ bb, float* __restrict__ out) {
  const int lane = threadIdx.x & 63, w = threadIdx.x >> 6;
  const float4 gv = *(const float4*)&g[lane * 4];
  const float4 bv = *(const float4*)&bb[lane * 4];
  const float4 cb = *(const float4*)&cbias[lane * 4];
  float* out2 = out + (size_t)2048 * 256;
  for (int r = blockIdx.x * 4 + w; r < 133120; r += 8192) {
    uint2 xu = *(const uint2*)&x[(size_t)r * 256 + lane * 4];
    uint2 du = *(const uint2*)&delta[(size_t)r * 256 + lane * 4];
    float v0 = __uint_as_float(xu.x << 16) + __uint_as_float(du.x << 16) + cb.x;
    float v1 = __uint_as_float(xu.x & 0xffff0000u) + __uint_as_float(du.x & 0xffff0000u) + cb.y;
    float v2 = __uint_as_float(xu.y << 16) + __uint_as_float(du.y << 16) + cb.z;
    float v3 = __uint_as_float(xu.y & 0xffff0000u) + __uint_as_float(du.y & 0xffff0000u) + cb.w;
    float mean = wave_sum(v0 + v1 + v2 + v3) * (1.0f / 256.0f);
    float d0 = v0 - mean, d1 = v1 - mean, d2 = v2 - mean, d3 = v3 - mean;
    float var = wave_sum(d0 * d0 + d1 * d1 + d2 * d2 + d3 * d3) * (1.0f / 256.0f);
    float rs = rsqrtf(var + 1e-5f);
    float4 y;
    y.x = d0 * rs * gv.x + bv.x;
    y.y = d1 * rs * gv.y + bv.y;
    y.z = d2 * rs * gv.z + bv.z;
    y.w = d3 * rs * gv.w + bv.w;
    const int b = r / 65, s = r - b * 65;
    float* dst = (s == 0) ? (out + (size_t)b * 256)
                          : (out2 + ((size_t)b * 64 + (s - 1)) * 256);
    *(float4*)&dst[lane * 4] = y;
  }
}

// Build T [131072][768] bf16: concat(edge-proj, nbr_table gather, msgs)
__global__ __launch_bounds__(512) void embed_k(
    const float* __restrict__ msgs, const float* __restrict__ edge_vec,
    const float* __restrict__ edge_dist, const int* __restrict__ enb,
    const float* __restrict__ edge_w, const float* __restrict__ edge_b,
    const float* __restrict__ nbr_table, u16* __restrict__ T) {
  const int r0 = blockIdx.x * 64, tid = threadIdx.x;
  __shared__ float tv[64][4];
  if (tid < 256) {
    int r = tid >> 2, j = tid & 3;
    tv[r][j] = (j < 3) ? edge_vec[(size_t)(r0 + r) * 3 + j] : edge_dist[r0 + r];
  }
  __syncthreads();
  for (int idx = tid; idx < 64 * 192; idx += 512) {
    int r = idx / 192, c4 = (idx % 192) * 4;
    size_t gn = (size_t)r0 + r;
    float4 v;
    if (c4 < 256) {
      float t0 = tv[r][0], t1 = tv[r][1], t2 = tv[r][2], t3 = tv[r][3];
      const float4 w0 = *(const float4*)&edge_w[c4];
      const float4 w1 = *(const float4*)&edge_w[256 + c4];
      const float4 w2 = *(const float4*)&edge_w[512 + c4];
      const float4 w3 = *(const float4*)&edge_w[768 + c4];
      const float4 eb4 = *(const float4*)&edge_b[c4];
      v.x = t0 * w0.x + t1 * w1.x + t2 * w2.x + t3 * w3.x + eb4.x;
      v.y = t0 * w0.y + t1 * w1.y + t2 * w2.y + t3 * w3.y + eb4.y;
      v.z = t0 * w0.z + t1 * w1.z + t2 * w2.z + t3 * w3.z + eb4.z;
      v.w = t0 * w0.w + t1 * w1.w + t2 * w2.w + t3 * w3.w + eb4.w;
    } else if (c4 < 512) {
      v = *(const float4*)&nbr_table[(size_t)enb[gn] * 256 + (c4 - 256)];
    } else {
      v = *(const float4*)&msgs[gn * 256 + (c4 - 512)];
    }
    uint2 p;
    p.x = f2b(v.x) | ((unsigned)f2b(v.y) << 16);
    p.y = f2b(v.z) | ((unsigned)f2b(v.w) << 16);
    *(uint2*)&T[gn * 768 + c4] = p;
  }
}

// node row s=0 per batch
__global__ __launch_bounds__(256) void node_row(
    const float* __restrict__ momenta, const int* __restrict__ ein,
    const float* __restrict__ node_table, const float* __restrict__ mom_w,
    const float* __restrict__ mom_b, const float* __restrict__ ncw,
    const float* __restrict__ ncb, u16* __restrict__ x) {
  const int b = blockIdx.x, tid = threadIdx.x;
  __shared__ float cvec[512];
  cvec[tid] = node_table[(size_t)ein[b] * 256 + tid];
  float m0 = momenta[b * 3], m1 = momenta[b * 3 + 1], m2 = momenta[b * 3 + 2];
  cvec[256 + tid] = m0 * mom_w[tid] + m1 * mom_w[256 + tid] + m2 * mom_w[512 + tid] + mom_b[tid];
  __syncthreads();
  float acc = 0.0f;
  for (int k = 0; k < 512; k += 4) {
    const float4 cv = *(const float4*)&cvec[k];
    acc += cv.x * ncw[(k + 0) * 256 + tid] + cv.y * ncw[(k + 1) * 256 + tid] +
           cv.z * ncw[(k + 2) * 256 + tid] + cv.w * ncw[(k + 3) * 256 + tid];
  }
  x[(size_t)b * 65 * 256 + tid] = f2b(acc + ncb[tid]);
}

// MFMA attention: block = (b, head-pair), 4 waves, 2 waves per head.
__global__ __launch_bounds__(256, 2) void attn_k2(
    const u16* __restrict__ qkv, const float* __restrict__ cutoff,
    u16* __restrict__ o) {
  const int b = blockIdx.x, hp = blockIdx.y;
  const int tid = threadIdx.x, lane = tid & 63, w = tid >> 6;
  const int lr = lane & 15, lg = lane >> 4;
  const int hl = w >> 1, wp = w & 1;
  const size_t bs0 = (size_t)b * 65;

  __shared__ __align__(16) u16 Qs[2][80][40];
  __shared__ __align__(16) u16 Ks[2][80][40];
  __shared__ __align__(16) u16 Vt[2][32][104];
  __shared__ __align__(16) u16 Ps[2][80][104];
  __shared__ float bias_s[80];

  if (tid < 80) {
    float bv;
    if (tid == 0) bv = 0.0f;
    else if (tid < 65) {
      float cf = cutoff[b * 64 + tid - 1];
      bv = (cf > 0.0f) ? logf(fmaxf(cf, 1e-30f)) : -1e9f;
    } else bv = -1e9f;
    bias_s[tid] = bv;
  }
  for (int idx = tid; idx < 2 * 80 * 4; idx += 256) {
    int h2 = idx / 320, rem = idx - h2 * 320;
    int q = rem >> 2, j = rem & 3;
    *(uint2*)&Ps[h2][q][80 + j * 4] = make_uint2(0, 0);
  }
  for (int idx = tid; idx < 2 * 32 * 4; idx += 256) {
    int h2 = idx / 128, rem = idx - h2 * 128;
    int d = rem >> 2, j = rem & 3;
    *(uint2*)&Vt[h2][d][80 + j * 4] = make_uint2(0, 0);
  }
  for (int idx = tid; idx < 2 * 80 * 8; idx += 256) {
    int h2 = idx / 640, rem = idx - h2 * 640;
    int s = rem >> 3, c4 = (rem & 7) << 2;
    uint2 vq = make_uint2(0, 0), vk = vq, vv = vq;
    if (s < 65) {
      const u16* base = qkv + (bs0 + s) * 768 + (hp * 2 + h2) * 32 + c4;
      vq = *(const uint2*)(base);
      vk = *(const uint2*)(base + 256);
      vv = *(const uint2*)(base + 512);
    }
    *(uint2*)&Qs[h2][s][c4] = vq;
    *(uint2*)&Ks[h2][s][c4] = vk;
    Vt[h2][c4 + 0][s] = (u16)(vv.x & 0xffffu);
    Vt[h2][c4 + 1][s] = (u16)(vv.x >> 16);
    Vt[h2][c4 + 2][s] = (u16)(vv.y & 0xffffu);
    Vt[h2][c4 + 3][s] = (u16)(vv.y >> 16);
  }
  __syncthreads();

  const int nt0 = wp ? 3 : 0, nt1 = wp ? 5 : 3;
  for (int nt = nt0; nt < nt1; ++nt) {
    s16x8 bq = *(const s16x8*)&Qs[hl][nt * 16 + lr][lg * 8];
    f32x4 sacc[5];
#pragma unroll
    for (int mt = 0; mt < 5; ++mt) {
      s16x8 ak = *(const s16x8*)&Ks[hl][mt * 16 + lr][lg * 8];
      f32x4 z = {0.f, 0.f, 0.f, 0.f};
      sacc[mt] = MFMA16(ak, bq, z);
    }
    float pv[5][4];
    float cmax = -3e38f;
#pragma unroll
    for (int mt = 0; mt < 5; ++mt)
#pragma unroll
      for (int e = 0; e < 4; ++e) {
        float v = sacc[mt][e] * 0.17677669529663687f + bias_s[mt * 16 + lg * 4 + e];
        pv[mt][e] = v;
        cmax = fmaxf(cmax, v);
      }
    cmax = fmaxf(cmax, __shfl_xor(cmax, 16));
    cmax = fmaxf(cmax, __shfl_xor(cmax, 32));
    float csum = 0.f;
#pragma unroll
    for (int mt = 0; mt < 5; ++mt)
#pragma unroll
      for (int e = 0; e < 4; ++e) {
        float p = __expf(pv[mt][e] - cmax);
        pv[mt][e] = p;
        csum += p;
      }
    csum += __shfl_xor(csum, 16);
    csum += __shfl_xor(csum, 32);
    float rinv = 1.0f / csum;
    const int q = nt * 16 + lr;
#pragma unroll
    for (int mt = 0; mt < 5; ++mt) {
      uint2 pk;
      pk.x = (unsigned)f2b(pv[mt][0] * rinv) | ((unsigned)f2b(pv[mt][1] * rinv) << 16);
      pk.y = (unsigned)f2b(pv[mt][2] * rinv) | ((unsigned)f2b(pv[mt][3] * rinv) << 16);
      *(uint2*)&Ps[hl][q][mt * 16 + lg * 4] = pk;
    }
  }
  __syncthreads();

  s16x8 vb[2][3];
#pragma unroll
  for (int d2 = 0; d2 < 2; ++d2)
#pragma unroll
    for (int ks = 0; ks < 3; ++ks)
      vb[d2][ks] = *(const s16x8*)&Vt[hl][d2 * 16 + lr][ks * 32 + lg * 8];
  const int mt0 = wp ? 3 : 0, mt1 = wp ? 5 : 3;
  for (int mt = mt0; mt < mt1; ++mt) {
    f32x4 oa[2] = {};
#pragma unroll
    for (int ks = 0; ks < 3; ++ks) {
      s16x8 pa = *(const s16x8*)&Ps[hl][mt * 16 + lr][ks * 32 + lg * 8];
#pragma unroll
      for (int d2 = 0; d2 < 2; ++d2) oa[d2] = MFMA16(pa, vb[d2][ks], oa[d2]);
    }
#pragma unroll
    for (int e = 0; e < 4; ++e) {
      int q = mt * 16 + lg * 4 + e;
      if (q < 65) {
        u16* op = o + (bs0 + q) * 256 + hp * 64 + hl * 32;
        op[lr] = f2b(oa[0][e]);
        op[16 + lr] = f2b(oa[1][e]);
      }
    }
  }
}

// =====================================================================

extern "C" void kernel_launch(void* const* d_in, const int* in_sizes, int n_in,
                              void* d_out, int out_size, void* d_ws, size_t ws_size,
                              hipStream_t stream) {
  (void)in_sizes; (void)n_in; (void)out_size; (void)ws_size;
  const float* msgs      = (const float*)d_in[0];
  const float* momenta   = (const float*)d_in[1];
  const float* edge_vec  = (const float*)d_in[2];
  const float* edge_dist = (const float*)d_in[3];
  const float* cutoff    = (const float*)d_in[4];
  const int* ein = (const int*)d_in[6];
  const int* enb = (const int*)d_in[7];
  const float* edge_w     = (const float*)d_in[8];
  const float* edge_b     = (const float*)d_in[9];
  const float* node_table = (const float*)d_in[10];
  const float* mom_w      = (const float*)d_in[11];
  const float* mom_b      = (const float*)d_in[12];
  const float* ncw        = (const float*)d_in[13];
  const float* ncb        = (const float*)d_in[14];
  const float* nbr_table  = (const float*)d_in[15];
  const float* cw1        = (const float*)d_in[16];
  const float* cb1        = (const float*)d_in[17];
  const float* cw2        = (const float*)d_in[18];
  const float* cb2        = (const float*)d_in[19];
  const float* qkv_w      = (const float*)d_in[20];
  const float* qkv_b      = (const float*)d_in[21];
  const float* aow        = (const float*)d_in[22];
  const float* aob        = (const float*)d_in[23];
  const float* ln1g       = (const float*)d_in[24];
  const float* ln1b       = (const float*)d_in[25];
  const float* fw1        = (const float*)d_in[26];
  const float* fb1        = (const float*)d_in[27];
  const float* fw2        = (const float*)d_in[28];
  const float* fb2        = (const float*)d_in[29];
  const float* ln2g       = (const float*)d_in[30];
  const float* ln2b       = (const float*)d_in[31];

  u16* ws = (u16*)d_ws;
  u16* cw1t  = ws + CW1T_OFF;
  u16* cw2t  = ws + CW2T_OFF;
  u16* qkvwt = ws + QKVWT_OFF;
  u16* aowt  = ws + AOWT_OFF;
  u16* fw1t  = ws + FW1T_OFF;
  u16* fw2t  = ws + FW2T_OFF;

  wconv<<<dim3((768 * 256 + 255) / 256, 1), 256, 0, stream>>>(cw1, cw1t, 768, 256);
  wconv<<<dim3((256 * 256 + 255) / 256, 1), 256, 0, stream>>>(cw2, cw2t, 256, 256);
  wconv<<<dim3((256 * 768 + 255) / 256, 3), 256, 0, stream>>>(qkv_w, qkvwt, 256, 768);
  wconv<<<dim3((256 * 256 + 255) / 256, 3), 256, 0, stream>>>(aow, aowt, 256, 256);
  wconv<<<dim3((256 * 1024 + 255) / 256, 3), 256, 0, stream>>>(fw1, fw1t, 256, 1024);
  wconv<<<dim3((1024 * 256 + 255) / 256, 3), 256, 0, stream>>>(fw2, fw2t, 1024, 256);

  u16* x    = (u16*)((char*)d_ws + X_OFF);
  u16* oslt = (u16*)((char*)d_ws + OSLOT_OFF);
  u16* big  = (u16*)((char*)d_ws + BIG_OFF);

  embed_k<<<2048, 512, 0, stream>>>(msgs, edge_vec, edge_dist, enb, edge_w,
                                    edge_b, nbr_table, big);
  gemm_bt<131072, 256, 768, 2><<<1024, 512, 0, stream>>>(big, cw1t, cb1, oslt);
  gemm_bt<131072, 256, 256, 3><<<1024, 512, 0, stream>>>(oslt, cw2t, cb2, x);
  node_row<<<2048, 256, 0, stream>>>(momenta, ein, node_table, mom_w, mom_b,
                                     ncw, ncb, x);
  for (int l = 0; l < 3; ++l) {
    gemm_bt<133120, 768, 256, 1><<<3120, 512, 0, stream>>>(
        x, qkvwt + (size_t)l * 196608, qkv_b + l * 768, big);
    attn_k2<<<dim3(2048, 4), 256, 0, stream>>>(big, cutoff, oslt);
    gemm_bt<133120, 256, 256, 0><<<1040, 512, 0, stream>>>(
        oslt, aowt + (size_t)l * 65536, aob, big);
    resln<<<2048, 256, 0, stream>>>(x, big, aob + l * 256, ln1g + l * 256,
                                    ln1b + l * 256);
    gemm_bt<133120, 1024, 256, 2><<<4160, 512, 0, stream>>>(
        x, fw1t + (size_t)l * 262144, fb1 + l * 1024, big);
    gemm_bt<133120, 256, 1024, 0><<<1040, 512, 0, stream>>>(
        big, fw2t + (size_t)l * 262144, fb2, oslt);
    if (l < 2) {
      resln<<<2048, 256, 0, stream>>>(x, oslt, fb2 + l * 256, ln2g + l * 256,
                                      ln2b + l * 256);
    } else {
      resln_out<<<2048, 256, 0, stream>>>(x, oslt, fb2 + l * 256,
                                          ln2g + l * 256, ln2b + l * 256,
                                          (float*)d_out);
    }
  }
}